// Round 6
// baseline (132.472 us; speedup 1.0000x reference)
//
#include <hip/hip_runtime.h>
#include <stdint.h>

#define INDIM   1024
#define OUTDIM  1024
#define BM 128
#define BN 128
#define BK 64
#define KTILES (INDIM / BK)    // 16

typedef __attribute__((ext_vector_type(8))) short  short8;   // 8 bf16 (4 VGPRs)
typedef __attribute__((ext_vector_type(4))) float  floatx4;  // MFMA acc

// ---------------- build dense W^T (fp32, handles duplicate (i,o) by add) ----
__global__ void k_scatter_w(const int* __restrict__ ind_in, const int* __restrict__ ind_out,
                            const float* __restrict__ w, float* __restrict__ W32T, int nnz) {
    int k = blockIdx.x * 256 + threadIdx.x;
    if (k < nnz)
        atomicAdd(&W32T[(size_t)ind_out[k] * INDIM + ind_in[k]], w[k]);
}

// ---------------- fp32 -> bf16 (RNE) for A and W^T ----------------
__device__ __forceinline__ uint32_t bf16pack(float x, float y) {
    uint32_t ux = __float_as_uint(x);
    ux = ((ux + 0x7FFFu + ((ux >> 16) & 1u)) >> 16) & 0xFFFFu;   // low  = x
    uint32_t uy = __float_as_uint(y);
    uy = (uy + 0x7FFFu + ((uy >> 16) & 1u)) & 0xFFFF0000u;       // high = y
    return ux | uy;
}

__global__ void k_convert(const float4* __restrict__ A, uint2* __restrict__ A16, int nA4,
                          const float4* __restrict__ Wt, uint2* __restrict__ W16, int nW4) {
    int i = blockIdx.x * 256 + threadIdx.x;
    int stride = gridDim.x * 256;
    for (int j = i; j < nA4; j += stride) {
        float4 v = A[j];
        A16[j] = make_uint2(bf16pack(v.x, v.y), bf16pack(v.z, v.w));
    }
    for (int j = i; j < nW4; j += stride) {
        float4 v = Wt[j];
        W16[j] = make_uint2(bf16pack(v.x, v.y), bf16pack(v.z, v.w));
    }
}

// ---------------- bf16 MFMA GEMM: C[M][1024] = A[M][1024] * W^T[1024][1024]^T + bias
// m97-shape: 128x128 tile, 256 threads (4 waves), each wave 4x4 tiles of
// 16x16x32. LDS rows hold 8 16B-chunks xor-swizzled by (row&7) so frag reads
// (16 lanes, 128B row stride) spread across all 8 bank-groups (2-way = free).
// Verified layouts (guide §3): A-frag m=lane&15,k=quad*8+j; B-frag n=lane&15,
// same k; C/D col=lane&15, row=quad*4+reg.
__global__ __launch_bounds__(256) void k_gemm(
    const ushort* __restrict__ A16,   // [M][1024] bf16 row-major
    const ushort* __restrict__ W16T,  // [1024 n][1024 k] bf16 row-major
    const float* __restrict__ bias,
    float* __restrict__ C, int M)
{
    __shared__ ushort lA[BM * BK];   // 16 KB
    __shared__ ushort lB[BN * BK];   // 16 KB

    const int t      = threadIdx.x;
    const int w      = t >> 6;
    const int L      = t & 63;
    const int lane15 = L & 15;
    const int lane7  = L & 7;
    const int quad   = L >> 4;
    const int wm     = w >> 1, wn = w & 1;

    const int bm0 = (blockIdx.x >> 3) * BM;
    const int bn0 = (blockIdx.x & 7) * BN;

    // staging geometry: chunk c = w*256 + q*64 + L; row = c>>3 (= w*32+q*8+(L>>3));
    // slot = c&7 (= L&7). Stored global chunk index = slot ^ (row&7), and
    // row&7 = L>>3 here, so the fetched chunk j8g is per-thread constant.
    const int srow_base = w * 32 + (L >> 3);          // + q*8
    const int j8g       = (L & 7) ^ (L >> 3);
    const int cbase     = w * 256 + L;                // + q*64

    const ushort* Abase = A16  + (size_t)bm0 * INDIM;
    const ushort* Bbase = W16T + (size_t)bn0 * INDIM;

    floatx4 acc[4][4] = {};

    for (int kt = 0; kt < KTILES; ++kt) {
        // ---- issue global loads first (overlap latency with barrier) ----
        uint4 va[4], vb[4];
        #pragma unroll
        for (int q = 0; q < 4; ++q) {
            const size_t goff = (size_t)(srow_base + q * 8) * INDIM + kt * BK + j8g * 8;
            va[q] = *(const uint4*)(Abase + goff);
            vb[q] = *(const uint4*)(Bbase + goff);
        }
        __syncthreads();                 // previous iter done reading LDS
        #pragma unroll
        for (int q = 0; q < 4; ++q) {
            *(uint4*)(lA + (size_t)(cbase + q * 64) * 8) = va[q];
            *(uint4*)(lB + (size_t)(cbase + q * 64) * 8) = vb[q];
        }
        __syncthreads();                 // writes visible

        #pragma unroll
        for (int ks = 0; ks < 2; ++ks) {
            const int koff = (((ks * 4 + quad) ^ lane7) * 8);
            short8 af[4], bf[4];
            #pragma unroll
            for (int tm = 0; tm < 4; ++tm)
                af[tm] = *(const short8*)(lA + (wm * 64 + tm * 16 + lane15) * 64 + koff);
            #pragma unroll
            for (int tn = 0; tn < 4; ++tn)
                bf[tn] = *(const short8*)(lB + (wn * 64 + tn * 16 + lane15) * 64 + koff);
            #pragma unroll
            for (int tm = 0; tm < 4; ++tm)
                #pragma unroll
                for (int tn = 0; tn < 4; ++tn)
                    acc[tm][tn] = __builtin_amdgcn_mfma_f32_16x16x32_bf16(
                        af[tm], bf[tn], acc[tm][tn], 0, 0, 0);
        }
    }

    // ---- epilogue: bias + store ----
    float bv[4];
    #pragma unroll
    for (int tn = 0; tn < 4; ++tn)
        bv[tn] = bias[bn0 + wn * 64 + tn * 16 + lane15];

    #pragma unroll
    for (int tm = 0; tm < 4; ++tm) {
        #pragma unroll
        for (int tn = 0; tn < 4; ++tn) {
            const int col = bn0 + wn * 64 + tn * 16 + lane15;
            #pragma unroll
            for (int r = 0; r < 4; ++r) {
                const int row = bm0 + wm * 64 + tm * 16 + quad * 4 + r;
                C[(size_t)row * OUTDIM + col] = acc[tm][tn][r] + bv[tn];
            }
        }
    }
}

// ---------------- launcher ----------------
extern "C" void kernel_launch(void* const* d_in, const int* in_sizes, int n_in,
                              void* d_out, int out_size, void* d_ws, size_t ws_size,
                              hipStream_t stream) {
    const float* input  = (const float*)d_in[0];
    const float* weight = (const float*)d_in[1];
    const float* bias   = (const float*)d_in[2];
    const int*   ind_in  = (const int*)d_in[3];
    const int*   ind_out = (const int*)d_in[4];
    float* out = (float*)d_out;

    const int nnz = in_sizes[1];
    const int M   = out_size / OUTDIM;      // 4096 (multiple of BM)

    char* ws = (char*)d_ws;
    float*  W32T = (float*)ws;                       // 4 MB  @ 0
    ushort* W16T = (ushort*)(ws + (4u << 20));       // 2 MB  @ 4 MB
    ushort* A16  = (ushort*)(ws + (6u << 20));       // 2*M*1024 B @ 6 MB

    (void)hipMemsetAsync(W32T, 0, (size_t)OUTDIM * INDIM * sizeof(float), stream);
    k_scatter_w<<<(nnz + 255) / 256, 256, 0, stream>>>(ind_in, ind_out, weight, W32T, nnz);
    k_convert<<<2048, 256, 0, stream>>>((const float4*)input, (uint2*)A16, M * INDIM / 4,
                                        (const float4*)W32T, (uint2*)W16T, OUTDIM * INDIM / 4);
    k_gemm<<<(M / BM) * (OUTDIM / BN), 256, 0, stream>>>(A16, W16T, bias, out, M);
}

// Round 7
// 99.613 us; speedup vs baseline: 1.3299x; 1.3299x over previous
//
#include <hip/hip_runtime.h>
#include <stdint.h>

#define INDIM   1024
#define OUTDIM  1024
#define BM 64
#define BN 64
#define BK 64
#define KTILES (INDIM / BK)    // 16

typedef __attribute__((ext_vector_type(8))) short  short8;   // 8 bf16 (4 VGPRs)
typedef __attribute__((ext_vector_type(4))) float  floatx4;  // MFMA acc

// ---------------- build dense W^T (fp32, handles duplicate (i,o) by add) ----
__global__ void k_scatter_w(const int* __restrict__ ind_in, const int* __restrict__ ind_out,
                            const float* __restrict__ w, float* __restrict__ W32T, int nnz) {
    int k = blockIdx.x * 256 + threadIdx.x;
    if (k < nnz)
        atomicAdd(&W32T[(size_t)ind_out[k] * INDIM + ind_in[k]], w[k]);
}

// ---------------- fp32 -> bf16 (RNE) for A and W^T ----------------
__device__ __forceinline__ uint32_t bf16pack(float x, float y) {
    uint32_t ux = __float_as_uint(x);
    ux = ((ux + 0x7FFFu + ((ux >> 16) & 1u)) >> 16) & 0xFFFFu;   // low  = x
    uint32_t uy = __float_as_uint(y);
    uy = (uy + 0x7FFFu + ((uy >> 16) & 1u)) & 0xFFFF0000u;       // high = y
    return ux | uy;
}

__global__ void k_convert(const float4* __restrict__ A, uint2* __restrict__ A16, int nA4,
                          const float4* __restrict__ Wt, uint2* __restrict__ W16, int nW4) {
    int i = blockIdx.x * 256 + threadIdx.x;
    int stride = gridDim.x * 256;
    for (int j = i; j < nA4; j += stride) {
        float4 v = A[j];
        A16[j] = make_uint2(bf16pack(v.x, v.y), bf16pack(v.z, v.w));
    }
    for (int j = i; j < nW4; j += stride) {
        float4 v = Wt[j];
        W16[j] = make_uint2(bf16pack(v.x, v.y), bf16pack(v.z, v.w));
    }
}

// ---------------- bf16 MFMA GEMM: C[M][1024] = A * W^T^T + bias ------------
// R7: 64x64 tile -> 1024 blocks = 4 blocks/CU = 16 waves/CU (R6 died at
// 1 block/CU: barriers exposed full global latency, MfmaUtil 5.7%).
// 4 waves, wave tile 32x32 = 2x2 of 16x16x32. XOR chunk swizzle kept
// (R6 measured SQ_LDS_BANK_CONFLICT = 0). Verified layouts (guide §3):
// A-frag m=lane&15,k=quad*8+j; B-frag n=lane&15; C/D col=lane&15,row=quad*4+r.
__global__ __launch_bounds__(256, 4) void k_gemm(
    const ushort* __restrict__ A16,   // [M][1024] bf16 row-major
    const ushort* __restrict__ W16T,  // [1024 n][1024 k] bf16 row-major
    const float* __restrict__ bias,
    float* __restrict__ C, int M)
{
    __shared__ ushort lA[BM * BK];   // 8 KB
    __shared__ ushort lB[BN * BK];   // 8 KB

    const int t      = threadIdx.x;
    const int w      = t >> 6;
    const int L      = t & 63;
    const int lane15 = L & 15;
    const int lane7  = L & 7;
    const int quad   = L >> 4;
    const int wm     = w >> 1, wn = w & 1;

    // XCD-aware swizzle: bid = r<<7 | n<<3 | x. Assuming XCD = bid&7 (round
    // robin), XCD x owns A rows [x*512, x*512+512) -> per-XCD L2 set =
    // 1 MB A + 2 MB B = 3 MB < 4 MB. Heuristic only - correctness unaffected.
    const int bid = blockIdx.x;
    const int bm0 = ((bid & 7) * 8 + (bid >> 7)) * BM;
    const int bn0 = ((bid >> 3) & 15) * BN;

    // staging: 512 chunks (16B) per tile; thread t stages chunks c=t (row
    // t>>3) and c=t+256 (row t>>3+32). slot = t&7; stored global chunk is
    // slot ^ (row&7); rows 32 apart share (row&7) -> one j8 per thread.
    const int srow = t >> 3;                       // 0..31
    const int j8   = (t & 7) ^ (srow & 7);

    const ushort* Abase = A16  + (size_t)bm0 * INDIM;
    const ushort* Bbase = W16T + (size_t)bn0 * INDIM;

    floatx4 acc[2][2] = {};

    for (int kt = 0; kt < KTILES; ++kt) {
        const int gcol = kt * BK + j8 * 8;
        uint4 va0 = *(const uint4*)(Abase + (size_t)srow        * INDIM + gcol);
        uint4 va1 = *(const uint4*)(Abase + (size_t)(srow + 32) * INDIM + gcol);
        uint4 vb0 = *(const uint4*)(Bbase + (size_t)srow        * INDIM + gcol);
        uint4 vb1 = *(const uint4*)(Bbase + (size_t)(srow + 32) * INDIM + gcol);
        __syncthreads();                 // previous iter done reading LDS
        *(uint4*)(lA + (size_t)t * 8)         = va0;
        *(uint4*)(lA + (size_t)(t + 256) * 8) = va1;
        *(uint4*)(lB + (size_t)t * 8)         = vb0;
        *(uint4*)(lB + (size_t)(t + 256) * 8) = vb1;
        __syncthreads();                 // writes visible

        #pragma unroll
        for (int ks = 0; ks < 2; ++ks) {
            const int koff = (((ks * 4 + quad) ^ lane7) * 8);
            short8 af[2], bf[2];
            #pragma unroll
            for (int tm = 0; tm < 2; ++tm)
                af[tm] = *(const short8*)(lA + (wm * 32 + tm * 16 + lane15) * 64 + koff);
            #pragma unroll
            for (int tn = 0; tn < 2; ++tn)
                bf[tn] = *(const short8*)(lB + (wn * 32 + tn * 16 + lane15) * 64 + koff);
            #pragma unroll
            for (int tm = 0; tm < 2; ++tm)
                #pragma unroll
                for (int tn = 0; tn < 2; ++tn)
                    acc[tm][tn] = __builtin_amdgcn_mfma_f32_16x16x32_bf16(
                        af[tm], bf[tn], acc[tm][tn], 0, 0, 0);
        }
    }

    // ---- epilogue: bias + store ----
    #pragma unroll
    for (int tm = 0; tm < 2; ++tm) {
        #pragma unroll
        for (int tn = 0; tn < 2; ++tn) {
            const int col = bn0 + wn * 32 + tn * 16 + lane15;
            const float bv = bias[col];
            #pragma unroll
            for (int r = 0; r < 4; ++r) {
                const int row = bm0 + wm * 32 + tm * 16 + quad * 4 + r;
                C[(size_t)row * OUTDIM + col] = acc[tm][tn][r] + bv;
            }
        }
    }
}

// ---------------- launcher ----------------
extern "C" void kernel_launch(void* const* d_in, const int* in_sizes, int n_in,
                              void* d_out, int out_size, void* d_ws, size_t ws_size,
                              hipStream_t stream) {
    const float* input  = (const float*)d_in[0];
    const float* weight = (const float*)d_in[1];
    const float* bias   = (const float*)d_in[2];
    const int*   ind_in  = (const int*)d_in[3];
    const int*   ind_out = (const int*)d_in[4];
    float* out = (float*)d_out;

    const int nnz = in_sizes[1];
    const int M   = out_size / OUTDIM;      // 4096 (multiple of BM)

    char* ws = (char*)d_ws;
    float*  W32T = (float*)ws;                       // 4 MB  @ 0
    ushort* W16T = (ushort*)(ws + (4u << 20));       // 2 MB  @ 4 MB
    ushort* A16  = (ushort*)(ws + (6u << 20));       // 2*M*1024 B @ 6 MB

    (void)hipMemsetAsync(W32T, 0, (size_t)OUTDIM * INDIM * sizeof(float), stream);
    k_scatter_w<<<(nnz + 255) / 256, 256, 0, stream>>>(ind_in, ind_out, weight, W32T, nnz);
    k_convert<<<2048, 256, 0, stream>>>((const float4*)input, (uint2*)A16, M * INDIM / 4,
                                        (const float4*)W32T, (uint2*)W16T, OUTDIM * INDIM / 4);
    k_gemm<<<(M / BM) * (OUTDIM / BN), 256, 0, stream>>>(A16, W16T, bias, out, M);
}